// Round 1
// baseline (959.615 us; speedup 1.0000x reference)
//
#include <hip/hip_runtime.h>
#include <cstdint>

// MoE layer: router top-2 (sigmoid gates) + 16 SwiGLU experts (1024->1024->1024)
// + shared SwiGLU expert (1024->2048->1024).
// Round 1: correctness-first fp32 tiled-GEMM pipeline with token compaction.
// All combines are position-deterministic (no float atomics).

#define N_TOK 2048
#define CDIM  1024
#define NEXP  16
#define TOPK  2
#define HDIM  1024
#define HH    2048   // 2*HDIM (gate_up output width)
#define SDIM  2048
#define LSTR  68     // LDS row stride in floats for 16-row tiles (16B-aligned, conflict-light)

// ---------------- router ----------------
__global__ void init_counts_kernel(int* counts) {
  if (threadIdx.x < NEXP) counts[threadIdx.x] = 0;
}

__global__ void router_kernel(const float* __restrict__ x,
                              const float* __restrict__ rw,
                              int* __restrict__ sel,
                              float* __restrict__ gatew,
                              int* __restrict__ counts) {
  int n = blockIdx.x;        // token
  int lane = threadIdx.x;    // 0..63 (one wave per token)
  const float* xr = x + (size_t)n * CDIM;
  float acc[NEXP];
#pragma unroll
  for (int e = 0; e < NEXP; ++e) acc[e] = 0.f;
  for (int i = lane; i < CDIM; i += 64) {
    float xi = xr[i];
#pragma unroll
    for (int e = 0; e < NEXP; ++e) acc[e] += xi * rw[e * CDIM + i];
  }
#pragma unroll
  for (int off = 32; off > 0; off >>= 1) {
#pragma unroll
    for (int e = 0; e < NEXP; ++e) acc[e] += __shfl_xor(acc[e], off, 64);
  }
  if (lane == 0) {
    // top-2 with first-index tie-breaking (matches jax.lax.top_k)
    int i0 = 0; float v0 = acc[0];
#pragma unroll
    for (int e = 1; e < NEXP; ++e) if (acc[e] > v0) { v0 = acc[e]; i0 = e; }
    int i1 = (i0 == 0) ? 1 : 0; float v1 = acc[i1];
#pragma unroll
    for (int e = 0; e < NEXP; ++e) if (e != i0 && acc[e] > v1) { v1 = acc[e]; i1 = e; }
    sel[2 * n] = i0; sel[2 * n + 1] = i1;
    gatew[2 * n]     = 1.f / (1.f + expf(-v0));
    gatew[2 * n + 1] = 1.f / (1.f + expf(-v1));
    atomicAdd(&counts[i0], 1);
    atomicAdd(&counts[i1], 1);
  }
}

__global__ void scan_kernel(const int* __restrict__ counts,
                            int* __restrict__ offsets,
                            int* __restrict__ cursor) {
  if (threadIdx.x == 0) {
    int s = 0;
    for (int e = 0; e < NEXP; ++e) { offsets[e] = s; cursor[e] = s; s += counts[e]; }
  }
}

__global__ void scatter_kernel(const int* __restrict__ sel,
                               const float* __restrict__ gatew,
                               int* __restrict__ cursor,
                               int* __restrict__ entry_token,
                               float* __restrict__ entry_gate,
                               int* __restrict__ entry_pos) {
  int t = blockIdx.x * blockDim.x + threadIdx.x;
  if (t >= N_TOK * TOPK) return;
  int e = sel[t];
  int pos = atomicAdd(&cursor[e], 1);
  entry_token[pos] = t >> 1;
  entry_gate[pos] = gatew[t];
  entry_pos[t] = pos;
}

// ---------------- expert gate_up + SwiGLU ----------------
// h_buf[entry][j] = silu(x[tok] @ W[e][:, j]) * (x[tok] @ W[e][:, j+1024])
__global__ __launch_bounds__(256)
void expert_gateup_kernel(const float* __restrict__ x,
                          const float* __restrict__ guw,  // [E][CDIM][HH]
                          const int* __restrict__ counts,
                          const int* __restrict__ offsets,
                          const int* __restrict__ entry_token,
                          float* __restrict__ h_buf) {    // [4096][HDIM]
  int e = blockIdx.z;
  int cnt = counts[e];
  int m0 = blockIdx.y * 64;
  if (m0 >= cnt) return;
  int base = offsets[e];
  int n0 = blockIdx.x * 64;          // gate col tile (0..1023)

  __shared__ __align__(16) float As[16 * LSTR];
  __shared__ __align__(16) float Bg[16 * LSTR];
  __shared__ __align__(16) float Bu[16 * LSTR];
  __shared__ int rowtok[64];

  int t = threadIdx.x;
  if (t < 64) {
    int r = m0 + t;
    rowtok[t] = (r < cnt) ? entry_token[base + r] : -1;
  }
  __syncthreads();

  int rbase = (t >> 4) * 4;
  int cbase = (t & 15) * 4;
  float accg[4][4] = {{0}}, accu[4][4] = {{0}};

  const float* wbase0 = guw + (size_t)e * CDIM * HH;
  for (int k0 = 0; k0 < CDIM; k0 += 16) {
#pragma unroll
    for (int q = 0; q < 4; ++q) {
      int idx = t + q * 256;
      int row = idx >> 4, kk = idx & 15;
      int tok = rowtok[row];
      As[kk * LSTR + row] = (tok >= 0) ? x[(size_t)tok * CDIM + k0 + kk] : 0.f;
    }
    const float* wb = wbase0 + (size_t)k0 * HH;
#pragma unroll
    for (int q = 0; q < 4; ++q) {
      int idx = t + q * 256;
      int kk = idx >> 6, j = idx & 63;
      Bg[kk * LSTR + j] = wb[(size_t)kk * HH + n0 + j];
      Bu[kk * LSTR + j] = wb[(size_t)kk * HH + HDIM + n0 + j];
    }
    __syncthreads();
#pragma unroll
    for (int kk = 0; kk < 16; ++kk) {
      float4 a4 = *(const float4*)&As[kk * LSTR + rbase];
      float4 g4 = *(const float4*)&Bg[kk * LSTR + cbase];
      float4 u4 = *(const float4*)&Bu[kk * LSTR + cbase];
      float av[4] = {a4.x, a4.y, a4.z, a4.w};
      float gv[4] = {g4.x, g4.y, g4.z, g4.w};
      float uv[4] = {u4.x, u4.y, u4.z, u4.w};
#pragma unroll
      for (int i = 0; i < 4; ++i)
#pragma unroll
        for (int j = 0; j < 4; ++j) {
          accg[i][j] = fmaf(av[i], gv[j], accg[i][j]);
          accu[i][j] = fmaf(av[i], uv[j], accu[i][j]);
        }
    }
    __syncthreads();
  }
#pragma unroll
  for (int i = 0; i < 4; ++i) {
    int r = m0 + rbase + i;
    if (r >= cnt) continue;
    int entry = base + r;
    float4 hv;
    float* hp = &hv.x;
#pragma unroll
    for (int j = 0; j < 4; ++j) {
      float g = accg[i][j], u = accu[i][j];
      hp[j] = (g / (1.f + expf(-g))) * u;
    }
    *(float4*)&h_buf[(size_t)entry * HDIM + n0 + cbase] = hv;
  }
}

// ---------------- expert down (fused gate scaling) ----------------
__global__ __launch_bounds__(256)
void expert_down_kernel(const float* __restrict__ h_buf,  // [4096][HDIM]
                        const float* __restrict__ dw,     // [E][HDIM][CDIM]
                        const int* __restrict__ counts,
                        const int* __restrict__ offsets,
                        const float* __restrict__ entry_gate,
                        float* __restrict__ out_e) {      // [4096][CDIM]
  int e = blockIdx.z;
  int cnt = counts[e];
  int m0 = blockIdx.y * 64;
  if (m0 >= cnt) return;
  int base = offsets[e];
  int n0 = blockIdx.x * 64;

  __shared__ __align__(16) float As[16 * LSTR];
  __shared__ __align__(16) float Bs[16 * LSTR];

  int t = threadIdx.x;
  int rbase = (t >> 4) * 4;
  int cbase = (t & 15) * 4;
  float acc[4][4] = {{0}};

  const float* wbase0 = dw + (size_t)e * HDIM * CDIM;
  for (int k0 = 0; k0 < HDIM; k0 += 16) {
#pragma unroll
    for (int q = 0; q < 4; ++q) {
      int idx = t + q * 256;
      int row = idx >> 4, kk = idx & 15;
      int r = m0 + row;
      As[kk * LSTR + row] = (r < cnt) ? h_buf[(size_t)(base + r) * HDIM + k0 + kk] : 0.f;
    }
    const float* wb = wbase0 + (size_t)k0 * CDIM;
#pragma unroll
    for (int q = 0; q < 4; ++q) {
      int idx = t + q * 256;
      int kk = idx >> 6, j = idx & 63;
      Bs[kk * LSTR + j] = wb[(size_t)kk * CDIM + n0 + j];
    }
    __syncthreads();
#pragma unroll
    for (int kk = 0; kk < 16; ++kk) {
      float4 a4 = *(const float4*)&As[kk * LSTR + rbase];
      float4 b4 = *(const float4*)&Bs[kk * LSTR + cbase];
      float av[4] = {a4.x, a4.y, a4.z, a4.w};
      float bv[4] = {b4.x, b4.y, b4.z, b4.w};
#pragma unroll
      for (int i = 0; i < 4; ++i)
#pragma unroll
        for (int j = 0; j < 4; ++j) acc[i][j] = fmaf(av[i], bv[j], acc[i][j]);
    }
    __syncthreads();
  }
#pragma unroll
  for (int i = 0; i < 4; ++i) {
    int r = m0 + rbase + i;
    if (r >= cnt) continue;
    int entry = base + r;
    float gsc = entry_gate[entry];
    float4 ov = {acc[i][0] * gsc, acc[i][1] * gsc, acc[i][2] * gsc, acc[i][3] * gsc};
    *(float4*)&out_e[(size_t)entry * CDIM + n0 + cbase] = ov;
  }
}

// ---------------- shared expert gate_up + SwiGLU (NT) ----------------
// h_s[n][s] = silu(x[n]@gw[s,:]) * (x[n]@uw[s,:])
__global__ __launch_bounds__(256)
void shared_gateup_kernel(const float* __restrict__ x,
                          const float* __restrict__ gw,   // [SDIM][CDIM]
                          const float* __restrict__ uw,   // [SDIM][CDIM]
                          float* __restrict__ h_s) {      // [N_TOK][SDIM]
  int m0 = blockIdx.y * 64;   // tokens
  int n0 = blockIdx.x * 64;   // s cols

  __shared__ __align__(16) float As[16 * LSTR];
  __shared__ __align__(16) float Bg[16 * LSTR];
  __shared__ __align__(16) float Bu[16 * LSTR];

  int t = threadIdx.x;
  int rbase = (t >> 4) * 4;
  int cbase = (t & 15) * 4;
  float accg[4][4] = {{0}}, accu[4][4] = {{0}};

  for (int k0 = 0; k0 < CDIM; k0 += 16) {
#pragma unroll
    for (int q = 0; q < 4; ++q) {
      int idx = t + q * 256;
      int row = idx >> 4, kk = idx & 15;
      As[kk * LSTR + row] = x[(size_t)(m0 + row) * CDIM + k0 + kk];
    }
#pragma unroll
    for (int q = 0; q < 4; ++q) {
      int idx = t + q * 256;
      int s_l = idx >> 4, c_l = idx & 15;
      Bg[c_l * LSTR + s_l] = gw[(size_t)(n0 + s_l) * CDIM + k0 + c_l];
      Bu[c_l * LSTR + s_l] = uw[(size_t)(n0 + s_l) * CDIM + k0 + c_l];
    }
    __syncthreads();
#pragma unroll
    for (int kk = 0; kk < 16; ++kk) {
      float4 a4 = *(const float4*)&As[kk * LSTR + rbase];
      float4 g4 = *(const float4*)&Bg[kk * LSTR + cbase];
      float4 u4 = *(const float4*)&Bu[kk * LSTR + cbase];
      float av[4] = {a4.x, a4.y, a4.z, a4.w};
      float gv[4] = {g4.x, g4.y, g4.z, g4.w};
      float uv[4] = {u4.x, u4.y, u4.z, u4.w};
#pragma unroll
      for (int i = 0; i < 4; ++i)
#pragma unroll
        for (int j = 0; j < 4; ++j) {
          accg[i][j] = fmaf(av[i], gv[j], accg[i][j]);
          accu[i][j] = fmaf(av[i], uv[j], accu[i][j]);
        }
    }
    __syncthreads();
  }
#pragma unroll
  for (int i = 0; i < 4; ++i) {
    int n = m0 + rbase + i;
    float4 hv;
    float* hp = &hv.x;
#pragma unroll
    for (int j = 0; j < 4; ++j) {
      float g = accg[i][j], u = accu[i][j];
      hp[j] = (g / (1.f + expf(-g))) * u;
    }
    *(float4*)&h_s[(size_t)n * SDIM + n0 + cbase] = hv;
  }
}

// ---------------- shared expert down (NT, K=2048), overwrites d_out ----------------
__global__ __launch_bounds__(256)
void shared_down_kernel(const float* __restrict__ h_s,   // [N_TOK][SDIM]
                        const float* __restrict__ dw,    // [CDIM][SDIM]
                        float* __restrict__ out) {       // [N_TOK][CDIM]
  int m0 = blockIdx.y * 64;
  int n0 = blockIdx.x * 64;

  __shared__ __align__(16) float As[16 * LSTR];
  __shared__ __align__(16) float Bs[16 * LSTR];

  int t = threadIdx.x;
  int rbase = (t >> 4) * 4;
  int cbase = (t & 15) * 4;
  float acc[4][4] = {{0}};

  for (int k0 = 0; k0 < SDIM; k0 += 16) {
#pragma unroll
    for (int q = 0; q < 4; ++q) {
      int idx = t + q * 256;
      int row = idx >> 4, kk = idx & 15;
      As[kk * LSTR + row] = h_s[(size_t)(m0 + row) * SDIM + k0 + kk];
    }
#pragma unroll
    for (int q = 0; q < 4; ++q) {
      int idx = t + q * 256;
      int j_l = idx >> 4, kk = idx & 15;
      Bs[kk * LSTR + j_l] = dw[(size_t)(n0 + j_l) * SDIM + k0 + kk];
    }
    __syncthreads();
#pragma unroll
    for (int kk = 0; kk < 16; ++kk) {
      float4 a4 = *(const float4*)&As[kk * LSTR + rbase];
      float4 b4 = *(const float4*)&Bs[kk * LSTR + cbase];
      float av[4] = {a4.x, a4.y, a4.z, a4.w};
      float bv[4] = {b4.x, b4.y, b4.z, b4.w};
#pragma unroll
      for (int i = 0; i < 4; ++i)
#pragma unroll
        for (int j = 0; j < 4; ++j) acc[i][j] = fmaf(av[i], bv[j], acc[i][j]);
    }
    __syncthreads();
  }
#pragma unroll
  for (int i = 0; i < 4; ++i) {
    int n = m0 + rbase + i;
    float4 ov = {acc[i][0], acc[i][1], acc[i][2], acc[i][3]};
    *(float4*)&out[(size_t)n * CDIM + n0 + cbase] = ov;
  }
}

// ---------------- combine: out += gated expert outputs (deterministic) ----------------
__global__ void combine_kernel(float* __restrict__ out,
                               const float* __restrict__ out_e,
                               const int* __restrict__ entry_pos) {
  int tid = blockIdx.x * blockDim.x + threadIdx.x;  // over N_TOK*CDIM/4
  int n = tid >> 8;         // CDIM/4 = 256 float4 per row
  int c4 = tid & 255;
  int p0 = entry_pos[2 * n];
  int p1 = entry_pos[2 * n + 1];
  float4 v = ((const float4*)out)[tid];
  float4 a = ((const float4*)out_e)[(size_t)p0 * 256 + c4];
  float4 b = ((const float4*)out_e)[(size_t)p1 * 256 + c4];
  v.x += a.x + b.x; v.y += a.y + b.y; v.z += a.z + b.z; v.w += a.w + b.w;
  ((float4*)out)[tid] = v;
}

extern "C" void kernel_launch(void* const* d_in, const int* in_sizes, int n_in,
                              void* d_out, int out_size, void* d_ws, size_t ws_size,
                              hipStream_t stream) {
  const float* x   = (const float*)d_in[0];
  const float* rw  = (const float*)d_in[1];
  const float* guw = (const float*)d_in[2];
  const float* dw  = (const float*)d_in[3];
  const float* sgw = (const float*)d_in[4];
  const float* suw = (const float*)d_in[5];
  const float* sdw = (const float*)d_in[6];
  float* out = (float*)d_out;
  char* ws = (char*)d_ws;

  // workspace layout
  int*   sel         = (int*)(ws + 0);          // 4096 ints
  float* gatew       = (float*)(ws + 16384);    // 4096 floats
  int*   counts      = (int*)(ws + 32768);      // 16
  int*   offsets     = (int*)(ws + 33024);      // 16
  int*   cursor      = (int*)(ws + 33280);      // 16
  int*   entry_token = (int*)(ws + 33536);      // 4096
  float* entry_gate  = (float*)(ws + 49920);    // 4096
  int*   entry_pos   = (int*)(ws + 66304);      // 4096
  float* h_buf       = (float*)(ws + 82944);    // 4096*1024 floats (16 MB), reused as [2048][2048]
  float* out_e       = (float*)(ws + 82944 + (size_t)4096 * 1024 * 4);  // 16 MB

  init_counts_kernel<<<1, 64, 0, stream>>>(counts);
  router_kernel<<<N_TOK, 64, 0, stream>>>(x, rw, sel, gatew, counts);
  scan_kernel<<<1, 64, 0, stream>>>(counts, offsets, cursor);
  scatter_kernel<<<16, 256, 0, stream>>>(sel, gatew, cursor, entry_token, entry_gate, entry_pos);

  // expert FFN (grouped GEMMs over compacted entries)
  expert_gateup_kernel<<<dim3(HDIM / 64, N_TOK / 64, NEXP), 256, 0, stream>>>(
      x, guw, counts, offsets, entry_token, h_buf);
  expert_down_kernel<<<dim3(CDIM / 64, N_TOK / 64, NEXP), 256, 0, stream>>>(
      h_buf, dw, counts, offsets, entry_gate, out_e);

  // shared expert (reuses h_buf after expert_down has consumed it)
  shared_gateup_kernel<<<dim3(SDIM / 64, N_TOK / 64), 256, 0, stream>>>(x, sgw, suw, h_buf);
  shared_down_kernel<<<dim3(CDIM / 64, N_TOK / 64), 256, 0, stream>>>(h_buf, sdw, out);

  // add gated expert contributions
  combine_kernel<<<(N_TOK * CDIM / 4) / 256, 256, 0, stream>>>(out, out_e, entry_pos);
}

// Round 2
// 411.668 us; speedup vs baseline: 2.3310x; 2.3310x over previous
//
#include <hip/hip_runtime.h>
#include <cstdint>

#define N_TOK 2048
#define CDIM  1024
#define NEXP  16
#define TOPK  2
#define HDIM  1024
#define SDIM  2048

typedef __bf16 bf16;
typedef __bf16 bf16x8 __attribute__((ext_vector_type(8)));
typedef float  f32x4  __attribute__((ext_vector_type(4)));
typedef unsigned int u32;

typedef __attribute__((address_space(3))) uint32_t lds_u32_t;
typedef __attribute__((address_space(1))) uint32_t glb_u32_t;

__device__ __forceinline__ void gload16(const void* g, void* l) {
  __builtin_amdgcn_global_load_lds((const glb_u32_t*)(uintptr_t)g,
                                   (lds_u32_t*)(uintptr_t)l, 16, 0, 0);
}

__device__ __forceinline__ unsigned short bfbits(float f) {
  union { bf16 h; unsigned short s; } u; u.h = (bf16)f; return u.s;
}
__device__ __forceinline__ float frombits(unsigned short s) {
  union { float f; u32 u; } z; z.u = ((u32)s) << 16; return z.f;
}

// ---------------- router ----------------
__global__ void init_counts_kernel(int* counts) {
  if (threadIdx.x < NEXP) counts[threadIdx.x] = 0;
}

__global__ void router_kernel(const float* __restrict__ x,
                              const float* __restrict__ rw,
                              int* __restrict__ sel,
                              float* __restrict__ gatew,
                              int* __restrict__ counts) {
  int n = blockIdx.x;
  int lane = threadIdx.x;
  const float* xr = x + (size_t)n * CDIM;
  float acc[NEXP];
#pragma unroll
  for (int e = 0; e < NEXP; ++e) acc[e] = 0.f;
  for (int i = lane; i < CDIM; i += 64) {
    float xi = xr[i];
#pragma unroll
    for (int e = 0; e < NEXP; ++e) acc[e] += xi * rw[e * CDIM + i];
  }
#pragma unroll
  for (int off = 32; off > 0; off >>= 1) {
#pragma unroll
    for (int e = 0; e < NEXP; ++e) acc[e] += __shfl_xor(acc[e], off, 64);
  }
  if (lane == 0) {
    int i0 = 0; float v0 = acc[0];
#pragma unroll
    for (int e = 1; e < NEXP; ++e) if (acc[e] > v0) { v0 = acc[e]; i0 = e; }
    int i1 = (i0 == 0) ? 1 : 0; float v1 = acc[i1];
#pragma unroll
    for (int e = 0; e < NEXP; ++e) if (e != i0 && acc[e] > v1) { v1 = acc[e]; i1 = e; }
    sel[2 * n] = i0; sel[2 * n + 1] = i1;
    gatew[2 * n]     = 1.f / (1.f + expf(-v0));
    gatew[2 * n + 1] = 1.f / (1.f + expf(-v1));
    atomicAdd(&counts[i0], 1);
    atomicAdd(&counts[i1], 1);
  }
}

__global__ void scan_kernel(const int* __restrict__ counts,
                            int* __restrict__ offsets,
                            int* __restrict__ cursor) {
  if (threadIdx.x == 0) {
    int s = 0;
    for (int e = 0; e < NEXP; ++e) { offsets[e] = s; cursor[e] = s; s += counts[e]; }
  }
}

__global__ void scatter_kernel(const int* __restrict__ sel,
                               const float* __restrict__ gatew,
                               int* __restrict__ cursor,
                               int* __restrict__ entry_token,
                               float* __restrict__ entry_gate,
                               int* __restrict__ entry_pos) {
  int t = blockIdx.x * blockDim.x + threadIdx.x;
  if (t >= N_TOK * TOPK) return;
  int e = sel[t];
  int pos = atomicAdd(&cursor[e], 1);
  entry_token[pos] = t >> 1;
  entry_gate[pos] = gatew[t];
  entry_pos[t] = pos;
}

// ---------------- fused gate_up GEMM (dual B phase, SwiGLU epilogue) ----------------
// A: fp32 [*,K] rows gathered (GROUPED) or identity. B phase0=gate, phase1=up.
// TRANSB=1: B fp32 [K][ldb] k-major (expert gate_up_w, up at col offset).
// TRANSB=0: B fp32 [N][ldb=K] n-major (shared gate/up weights, separate arrays).
// Out: bf16 h [rows][Nout].
template<int TRANSB, int GROUPED>
__global__ __launch_bounds__(256)
void gateup_gemm(const float* __restrict__ A,
                 const float* __restrict__ Bg,
                 const float* __restrict__ Bu,
                 size_t bexp_stride, int bu_coloff,
                 bf16* __restrict__ Hout,
                 const int* __restrict__ counts,
                 const int* __restrict__ offsets,
                 const int* __restrict__ entry_token,
                 int K, int ldb, int Nout, int Mfix) {
  __shared__ __align__(16) bf16 sA[128 * 64];
  __shared__ __align__(16) bf16 sB[128 * 64];
  __shared__ int rowtok[128];

  const int e = GROUPED ? blockIdx.z : 0;
  int cnt, base;
  if (GROUPED) { cnt = counts[e]; base = offsets[e]; }
  else { cnt = Mfix; base = 0; }
  const int m0 = blockIdx.y * 128;
  if (m0 >= cnt) return;
  const int n0 = blockIdx.x * 128;

  const int t = threadIdx.x;
  if (GROUPED) {
    if (t < 128) {
      int r = m0 + t;
      rowtok[t] = entry_token[base + ((r < cnt) ? r : 0)];
    }
    __syncthreads();
  }

  const int srow  = t >> 1;         // staging row for A (and NT-B)
  const int half4 = (t & 1) * 4;    // chunk base
  const float* Aq;
  if (GROUPED) Aq = A + (size_t)rowtok[srow] * K;
  else         Aq = A + (size_t)(m0 + srow) * K;

  const int kch = t >> 5;           // TRANSB k-chunk 0..7
  const int nb4 = (t & 31) * 4;

  const int wid = t >> 6, lane = t & 63;
  const int wr = (wid >> 1) * 64, wc = (wid & 1) * 64;
  const int lrow = lane & 15, grp = lane >> 4;

  f32x4 acc[4][4];
  u32 parked[4][4][2];

  const float* Bexp_g = Bg + (GROUPED ? (size_t)e * bexp_stride : 0);
  const float* Bexp_u = Bu + (GROUPED ? (size_t)e * bexp_stride : 0);

  for (int ph = 0; ph < 2; ++ph) {
    const float* Bp = ph ? Bexp_u : Bexp_g;
    const int ncol = n0 + (ph ? bu_coloff : 0);
#pragma unroll
    for (int m = 0; m < 4; ++m)
#pragma unroll
      for (int n = 0; n < 4; ++n)
#pragma unroll
        for (int i = 0; i < 4; ++i) acc[m][n][i] = 0.f;

    for (int k0 = 0; k0 < K; k0 += 64) {
      // ---- stage A (fp32 -> bf16, swizzled chunks)
#pragma unroll
      for (int q = 0; q < 4; ++q) {
        const int c = half4 + q;
        const float4 f0 = *(const float4*)(Aq + k0 + c * 8);
        const float4 f1 = *(const float4*)(Aq + k0 + c * 8 + 4);
        bf16x8 v;
        v[0]=(bf16)f0.x; v[1]=(bf16)f0.y; v[2]=(bf16)f0.z; v[3]=(bf16)f0.w;
        v[4]=(bf16)f1.x; v[5]=(bf16)f1.y; v[6]=(bf16)f1.z; v[7]=(bf16)f1.w;
        *(bf16x8*)&sA[srow * 64 + ((c ^ (srow & 7)) << 3)] = v;
      }
      // ---- stage B
      if (TRANSB) {
        bf16x8 w[4];
#pragma unroll
        for (int j = 0; j < 8; ++j) {
          const float4 fv = *(const float4*)(Bp + (size_t)(k0 + kch * 8 + j) * ldb + ncol + nb4);
          w[0][j]=(bf16)fv.x; w[1][j]=(bf16)fv.y; w[2][j]=(bf16)fv.z; w[3][j]=(bf16)fv.w;
        }
#pragma unroll
        for (int cc = 0; cc < 4; ++cc) {
          const int r = nb4 + cc;
          *(bf16x8*)&sB[r * 64 + ((kch ^ (r & 7)) << 3)] = w[cc];
        }
      } else {
        const float* Bq = Bp + (size_t)(n0 + srow) * ldb;
#pragma unroll
        for (int q = 0; q < 4; ++q) {
          const int c = half4 + q;
          const float4 f0 = *(const float4*)(Bq + k0 + c * 8);
          const float4 f1 = *(const float4*)(Bq + k0 + c * 8 + 4);
          bf16x8 v;
          v[0]=(bf16)f0.x; v[1]=(bf16)f0.y; v[2]=(bf16)f0.z; v[3]=(bf16)f0.w;
          v[4]=(bf16)f1.x; v[5]=(bf16)f1.y; v[6]=(bf16)f1.z; v[7]=(bf16)f1.w;
          *(bf16x8*)&sB[srow * 64 + ((c ^ (srow & 7)) << 3)] = v;
        }
      }
      __syncthreads();
      // ---- compute
#pragma unroll
      for (int kk = 0; kk < 2; ++kk) {
        const int ch = kk * 4 + grp;
        bf16x8 av[4], bv[4];
#pragma unroll
        for (int m = 0; m < 4; ++m) {
          const int r = wr + m * 16 + lrow;
          av[m] = *(const bf16x8*)&sA[r * 64 + ((ch ^ (r & 7)) << 3)];
        }
#pragma unroll
        for (int n = 0; n < 4; ++n) {
          const int r = wc + n * 16 + lrow;
          bv[n] = *(const bf16x8*)&sB[r * 64 + ((ch ^ (r & 7)) << 3)];
        }
#pragma unroll
        for (int m = 0; m < 4; ++m)
#pragma unroll
          for (int n = 0; n < 4; ++n)
            acc[m][n] = __builtin_amdgcn_mfma_f32_16x16x32_bf16(av[m], bv[n], acc[m][n], 0, 0, 0);
      }
      __syncthreads();
    }
    if (ph == 0) {
#pragma unroll
      for (int m = 0; m < 4; ++m)
#pragma unroll
        for (int n = 0; n < 4; ++n) {
          parked[m][n][0] = (u32)bfbits(acc[m][n][0]) | ((u32)bfbits(acc[m][n][1]) << 16);
          parked[m][n][1] = (u32)bfbits(acc[m][n][2]) | ((u32)bfbits(acc[m][n][3]) << 16);
        }
    }
  }
  // ---- epilogue: h = silu(gate) * up  (C/D layout: col=lane&15, row=grp*4+reg)
#pragma unroll
  for (int m = 0; m < 4; ++m) {
#pragma unroll
    for (int i = 0; i < 4; ++i) {
      const int rl = wr + m * 16 + grp * 4 + i;
      const int row = m0 + rl;
      if (GROUPED && row >= cnt) continue;
      bf16* orow = Hout + (size_t)(base + row) * Nout + n0;
#pragma unroll
      for (int n = 0; n < 4; ++n) {
        const u32 p = parked[m][n][i >> 1];
        const float g = frombits((i & 1) ? (unsigned short)(p >> 16)
                                         : (unsigned short)(p & 0xffffu));
        const float u = acc[m][n][i];
        orow[wc + n * 16 + lrow] = (bf16)(g * u / (1.f + __expf(-g)));
      }
    }
  }
}

// ---------------- down GEMM (bf16 A via global_load_lds, fp32 B staged) ----------------
template<int TRANSB, int GROUPED, int SCALE>
__global__ __launch_bounds__(256)
void down_gemm(const bf16* __restrict__ A,
               const float* __restrict__ B, size_t bexp_stride,
               float* __restrict__ Out,
               const int* __restrict__ counts,
               const int* __restrict__ offsets,
               const float* __restrict__ row_scale,
               int K, int ldb, int Nout, int Mfix, int Mlim) {
  __shared__ __align__(16) bf16 sA[128 * 64];
  __shared__ __align__(16) bf16 sB[128 * 64];

  const int e = GROUPED ? blockIdx.z : 0;
  int cnt, base;
  if (GROUPED) { cnt = counts[e]; base = offsets[e]; }
  else { cnt = Mfix; base = 0; }
  const int m0 = blockIdx.y * 128;
  if (m0 >= cnt) return;
  const int n0 = blockIdx.x * 128;

  const int t = threadIdx.x;
  const int wid = t >> 6, lane = t & 63;

  // per-lane A sources for global_load_lds (swizzle folded into source address)
  const bf16* asrc[4];
  int adst[4];
#pragma unroll
  for (int i = 0; i < 4; ++i) {
    const int blkc = wid * 4 + i;                 // 0..15 chunk-blocks
    const int row_l = blkc * 8 + (lane >> 3);     // 0..127
    const int c = (lane & 7) ^ (lane >> 3);       // content chunk (inverse swizzle)
    int rg = m0 + row_l;
    int row_g;
    if (GROUPED) { int x = base + rg; row_g = (x < Mlim) ? x : (Mlim - 1); }
    else row_g = rg;
    asrc[i] = A + (size_t)row_g * K + c * 8;
    adst[i] = blkc * 512;
  }

  const int kch = t >> 5;
  const int nb4 = (t & 31) * 4;
  const int srow = t >> 1;
  const int half4 = (t & 1) * 4;
  const float* Bq0 = B + (GROUPED ? (size_t)e * bexp_stride : 0);

  const int wr = (wid >> 1) * 64, wc = (wid & 1) * 64;
  const int lrow = lane & 15, grp = lane >> 4;

  f32x4 acc[4][4];
#pragma unroll
  for (int m = 0; m < 4; ++m)
#pragma unroll
    for (int n = 0; n < 4; ++n)
#pragma unroll
      for (int i = 0; i < 4; ++i) acc[m][n][i] = 0.f;

  for (int k0 = 0; k0 < K; k0 += 64) {
#pragma unroll
    for (int i = 0; i < 4; ++i) gload16(asrc[i] + k0, &sA[adst[i]]);
    if (TRANSB) {
      bf16x8 w[4];
#pragma unroll
      for (int j = 0; j < 8; ++j) {
        const float4 fv = *(const float4*)(Bq0 + (size_t)(k0 + kch * 8 + j) * ldb + n0 + nb4);
        w[0][j]=(bf16)fv.x; w[1][j]=(bf16)fv.y; w[2][j]=(bf16)fv.z; w[3][j]=(bf16)fv.w;
      }
#pragma unroll
      for (int cc = 0; cc < 4; ++cc) {
        const int r = nb4 + cc;
        *(bf16x8*)&sB[r * 64 + ((kch ^ (r & 7)) << 3)] = w[cc];
      }
    } else {
      const float* Bq = Bq0 + (size_t)(n0 + srow) * ldb;
#pragma unroll
      for (int q = 0; q < 4; ++q) {
        const int c = half4 + q;
        const float4 f0 = *(const float4*)(Bq + k0 + c * 8);
        const float4 f1 = *(const float4*)(Bq + k0 + c * 8 + 4);
        bf16x8 v;
        v[0]=(bf16)f0.x; v[1]=(bf16)f0.y; v[2]=(bf16)f0.z; v[3]=(bf16)f0.w;
        v[4]=(bf16)f1.x; v[5]=(bf16)f1.y; v[6]=(bf16)f1.z; v[7]=(bf16)f1.w;
        *(bf16x8*)&sB[srow * 64 + ((c ^ (srow & 7)) << 3)] = v;
      }
    }
    __syncthreads();
#pragma unroll
    for (int kk = 0; kk < 2; ++kk) {
      const int ch = kk * 4 + grp;
      bf16x8 av[4], bv[4];
#pragma unroll
      for (int m = 0; m < 4; ++m) {
        const int r = wr + m * 16 + lrow;
        av[m] = *(const bf16x8*)&sA[r * 64 + ((ch ^ (r & 7)) << 3)];
      }
#pragma unroll
      for (int n = 0; n < 4; ++n) {
        const int r = wc + n * 16 + lrow;
        bv[n] = *(const bf16x8*)&sB[r * 64 + ((ch ^ (r & 7)) << 3)];
      }
#pragma unroll
      for (int m = 0; m < 4; ++m)
#pragma unroll
        for (int n = 0; n < 4; ++n)
          acc[m][n] = __builtin_amdgcn_mfma_f32_16x16x32_bf16(av[m], bv[n], acc[m][n], 0, 0, 0);
    }
    __syncthreads();
  }
#pragma unroll
  for (int m = 0; m < 4; ++m) {
#pragma unroll
    for (int i = 0; i < 4; ++i) {
      const int rl = wr + m * 16 + grp * 4 + i;
      const int row = m0 + rl;
      if (GROUPED && row >= cnt) continue;
      float* orow = Out + (size_t)(base + row) * Nout + n0;
      const float sc = SCALE ? row_scale[base + row] : 1.f;
#pragma unroll
      for (int n = 0; n < 4; ++n)
        orow[wc + n * 16 + lrow] = acc[m][n][i] * sc;
    }
  }
}

// ---------------- combine ----------------
__global__ void combine_kernel(float* __restrict__ out,
                               const float* __restrict__ out_e,
                               const int* __restrict__ entry_pos) {
  int tid = blockIdx.x * blockDim.x + threadIdx.x;
  int n = tid >> 8;
  int c4 = tid & 255;
  int p0 = entry_pos[2 * n];
  int p1 = entry_pos[2 * n + 1];
  float4 v = ((const float4*)out)[tid];
  float4 a = ((const float4*)out_e)[(size_t)p0 * 256 + c4];
  float4 b = ((const float4*)out_e)[(size_t)p1 * 256 + c4];
  v.x += a.x + b.x; v.y += a.y + b.y; v.z += a.z + b.z; v.w += a.w + b.w;
  ((float4*)out)[tid] = v;
}

extern "C" void kernel_launch(void* const* d_in, const int* in_sizes, int n_in,
                              void* d_out, int out_size, void* d_ws, size_t ws_size,
                              hipStream_t stream) {
  const float* x   = (const float*)d_in[0];
  const float* rw  = (const float*)d_in[1];
  const float* guw = (const float*)d_in[2];
  const float* dw  = (const float*)d_in[3];
  const float* sgw = (const float*)d_in[4];
  const float* suw = (const float*)d_in[5];
  const float* sdw = (const float*)d_in[6];
  float* out = (float*)d_out;
  char* ws = (char*)d_ws;

  int*   sel         = (int*)(ws + 0);
  float* gatew       = (float*)(ws + 16384);
  int*   counts      = (int*)(ws + 32768);
  int*   offsets     = (int*)(ws + 33024);
  int*   cursor      = (int*)(ws + 33280);
  int*   entry_token = (int*)(ws + 33536);
  float* entry_gate  = (float*)(ws + 49920);
  int*   entry_pos   = (int*)(ws + 66304);
  bf16*  h_buf       = (bf16*)(ws + 82944);                       // 8 MB ([4096][1024] or [2048][2048])
  float* out_e       = (float*)(ws + 82944 + (size_t)8388608);    // 16 MB

  init_counts_kernel<<<1, 64, 0, stream>>>(counts);
  router_kernel<<<N_TOK, 64, 0, stream>>>(x, rw, sel, gatew, counts);
  scan_kernel<<<1, 64, 0, stream>>>(counts, offsets, cursor);
  scatter_kernel<<<16, 256, 0, stream>>>(sel, gatew, cursor, entry_token, entry_gate, entry_pos);

  // expert gate_up + SwiGLU -> h_buf[4096][1024] bf16
  gateup_gemm<1, 1><<<dim3(HDIM / 128, 16, NEXP), 256, 0, stream>>>(
      x, guw, guw, (size_t)CDIM * 2 * HDIM, HDIM, h_buf,
      counts, offsets, entry_token, CDIM, 2 * HDIM, HDIM, 0);

  // expert down (gate-scaled) -> out_e[4096][1024] fp32
  down_gemm<1, 1, 1><<<dim3(CDIM / 128, 16, NEXP), 256, 0, stream>>>(
      h_buf, dw, (size_t)HDIM * CDIM, out_e,
      counts, offsets, entry_gate, HDIM, CDIM, CDIM, 0, N_TOK * TOPK);

  // shared gate_up + SwiGLU -> h_buf[2048][2048] bf16 (reuses buffer)
  gateup_gemm<0, 0><<<dim3(SDIM / 128, N_TOK / 128, 1), 256, 0, stream>>>(
      x, sgw, suw, 0, 0, h_buf,
      nullptr, nullptr, nullptr, CDIM, CDIM, SDIM, N_TOK);

  // shared down -> d_out fp32
  down_gemm<0, 0, 0><<<dim3(CDIM / 128, N_TOK / 128, 1), 256, 0, stream>>>(
      h_buf, sdw, 0, out,
      nullptr, nullptr, nullptr, SDIM, SDIM, CDIM, N_TOK, N_TOK);

  // add gated expert contributions
  combine_kernel<<<(N_TOK * CDIM / 4) / 256, 256, 0, stream>>>(out, out_e, entry_pos);
}

// Round 3
// 348.813 us; speedup vs baseline: 2.7511x; 1.1802x over previous
//
#include <hip/hip_runtime.h>
#include <cstdint>

#define N_TOK 2048
#define CDIM  1024
#define NEXP  16
#define TOPK  2
#define HDIM  1024
#define SDIM  2048
#define ESLOT128 48   // max Sum_e ceil(cnt_e/128) = 4096/128 + 16
#define ESLOT64  80   // max Sum_e ceil(cnt_e/64)  = 4096/64  + 16

typedef __bf16 bf16;
typedef __bf16 bf16x8 __attribute__((ext_vector_type(8)));
typedef float  f32x4  __attribute__((ext_vector_type(4)));
typedef unsigned int u32;
typedef unsigned short u16;

typedef __attribute__((address_space(3))) uint32_t lds_u32_t;
typedef __attribute__((address_space(1))) uint32_t glb_u32_t;

__device__ __forceinline__ void gload16(const void* g, void* l) {
  __builtin_amdgcn_global_load_lds((const glb_u32_t*)(uintptr_t)g,
                                   (lds_u32_t*)(uintptr_t)l, 16, 0, 0);
}
__device__ __forceinline__ float fromb(u16 s) {
  union { float f; u32 u; } z; z.u = ((u32)s) << 16; return z.f;
}

// ---------------- router ----------------
__global__ void init_counts_kernel(int* counts) {
  if (threadIdx.x < NEXP) counts[threadIdx.x] = 0;
}

__global__ void router_kernel(const float* __restrict__ x,
                              const float* __restrict__ rw,
                              int* __restrict__ sel,
                              float* __restrict__ gatew,
                              int* __restrict__ counts) {
  int n = blockIdx.x;
  int lane = threadIdx.x;
  const float* xr = x + (size_t)n * CDIM;
  float acc[NEXP];
#pragma unroll
  for (int e = 0; e < NEXP; ++e) acc[e] = 0.f;
  for (int i = lane; i < CDIM; i += 64) {
    float xi = xr[i];
#pragma unroll
    for (int e = 0; e < NEXP; ++e) acc[e] += xi * rw[e * CDIM + i];
  }
#pragma unroll
  for (int off = 32; off > 0; off >>= 1) {
#pragma unroll
    for (int e = 0; e < NEXP; ++e) acc[e] += __shfl_xor(acc[e], off, 64);
  }
  if (lane == 0) {
    int i0 = 0; float v0 = acc[0];
#pragma unroll
    for (int e = 1; e < NEXP; ++e) if (acc[e] > v0) { v0 = acc[e]; i0 = e; }
    int i1 = (i0 == 0) ? 1 : 0; float v1 = acc[i1];
#pragma unroll
    for (int e = 0; e < NEXP; ++e) if (e != i0 && acc[e] > v1) { v1 = acc[e]; i1 = e; }
    sel[2 * n] = i0; sel[2 * n + 1] = i1;
    gatew[2 * n]     = 1.f / (1.f + expf(-v0));
    gatew[2 * n + 1] = 1.f / (1.f + expf(-v1));
    atomicAdd(&counts[i0], 1);
    atomicAdd(&counts[i1], 1);
  }
}

// scan + device-side tile tables (data-dependent grouped-GEMM tiling)
__global__ void scan_kernel(const int* __restrict__ counts,
                            int* __restrict__ offsets,
                            int* __restrict__ cursor,
                            int* __restrict__ tab128,
                            int* __restrict__ tab64,
                            int* __restrict__ ntiles) {
  if (threadIdx.x == 0) {
    int s = 0, a = 0, b = 0;
    for (int e = 0; e < NEXP; ++e) {
      offsets[e] = s; cursor[e] = s;
      int c = counts[e];
      for (int m0 = 0; m0 < c; m0 += 128) tab128[a++] = (e << 16) | m0;
      for (int m0 = 0; m0 < c; m0 += 64)  tab64[b++]  = (e << 16) | m0;
      s += c;
    }
    ntiles[0] = a; ntiles[1] = b;
  }
}

__global__ void scatter_kernel(const int* __restrict__ sel,
                               const float* __restrict__ gatew,
                               int* __restrict__ cursor,
                               int* __restrict__ entry_token,
                               float* __restrict__ entry_gate,
                               int* __restrict__ entry_pos) {
  int t = blockIdx.x * blockDim.x + threadIdx.x;
  if (t >= N_TOK * TOPK) return;
  int e = sel[t];
  int pos = atomicAdd(&cursor[e], 1);
  entry_token[pos] = t >> 1;
  entry_gate[pos] = gatew[t];
  entry_pos[t] = pos;
}

// ---------------- fused gate+up GEMM, single K-pass, expert+shared in one launch ----
// Tile 128 rows x 128 h-cols (consumes 128 gate cols + 128 up cols). 4 waves.
// Expert region (bid < ESLOT128*8): A = gathered x rows, B k-major guw[e], up at col+1024.
// Shared region: A = x rows direct, Bg/Bu n-major sgw/suw.
__global__ __launch_bounds__(256)
void gateup_fused(const float* __restrict__ x,
                  const float* __restrict__ guw,
                  const float* __restrict__ sgw,
                  const float* __restrict__ suw,
                  bf16* __restrict__ h_exp,
                  bf16* __restrict__ h_sh,
                  const int* __restrict__ counts,
                  const int* __restrict__ offsets,
                  const int* __restrict__ entry_token,
                  const int* __restrict__ tab128,
                  const int* __restrict__ ntiles) {
  __shared__ __align__(16) bf16 sA[128 * 64];
  __shared__ __align__(16) bf16 sBg[128 * 64];
  __shared__ __align__(16) bf16 sBu[128 * 64];
  __shared__ int rowtok[128];

  const int bid = blockIdx.x;
  const int t = threadIdx.x;
  const bool is_exp = bid < ESLOT128 * 8;

  const int srow  = t >> 1;
  const int half4 = (t & 1) * 4;
  const int kch = t >> 5;
  const int nb4 = (t & 31) * 4;

  int n0, mguard;
  const float* Aq;
  const float *Btg = nullptr, *Btu = nullptr;   // trans (k-major) bases, col-offset folded
  const float *Bdg = nullptr, *Bdu = nullptr;   // direct (n-major) per-thread row ptrs
  bf16* hbase;
  int hstride;

  if (is_exp) {
    const int slot = bid >> 3;
    if (slot >= ntiles[0]) return;
    const int packed = tab128[slot];
    const int e = packed >> 16;
    const int m0 = packed & 0xffff;
    const int cnt = counts[e];
    const int base = offsets[e];
    n0 = (bid & 7) * 128;
    mguard = cnt - m0;
    if (t < 128) {
      int r = m0 + t;
      rowtok[t] = entry_token[base + ((r < cnt) ? r : (cnt - 1))];
    }
    __syncthreads();
    Aq = x + (size_t)rowtok[srow] * CDIM;
    Btg = guw + (size_t)e * CDIM * 2 * HDIM + n0;
    Btu = Btg + HDIM;
    hbase = h_exp + (size_t)(base + m0) * HDIM + n0;
    hstride = HDIM;
  } else {
    const int sid = bid - ESLOT128 * 8;
    const int m0 = (sid >> 4) * 128;
    n0 = (sid & 15) * 128;
    mguard = 128;
    Aq = x + (size_t)(m0 + srow) * CDIM;
    Bdg = sgw + (size_t)(n0 + srow) * CDIM;
    Bdu = suw + (size_t)(n0 + srow) * CDIM;
    hbase = h_sh + (size_t)m0 * SDIM + n0;
    hstride = SDIM;
  }

  const int wid = t >> 6, lane = t & 63;
  const int wr = (wid >> 1) * 64, wc = (wid & 1) * 64;
  const int lrow = lane & 15, grp = lane >> 4;

  f32x4 ag[4][4], au[4][4];
#pragma unroll
  for (int m = 0; m < 4; ++m)
#pragma unroll
    for (int n = 0; n < 4; ++n)
#pragma unroll
      for (int i = 0; i < 4; ++i) { ag[m][n][i] = 0.f; au[m][n][i] = 0.f; }

  for (int k0 = 0; k0 < CDIM; k0 += 64) {
    // ---- stage A (fp32 -> bf16, chunk-swizzled)
#pragma unroll
    for (int q = 0; q < 4; ++q) {
      const int c = half4 + q;
      const float4 f0 = *(const float4*)(Aq + k0 + c * 8);
      const float4 f1 = *(const float4*)(Aq + k0 + c * 8 + 4);
      bf16x8 v;
      v[0]=(bf16)f0.x; v[1]=(bf16)f0.y; v[2]=(bf16)f0.z; v[3]=(bf16)f0.w;
      v[4]=(bf16)f1.x; v[5]=(bf16)f1.y; v[6]=(bf16)f1.z; v[7]=(bf16)f1.w;
      *(bf16x8*)&sA[srow * 64 + ((c ^ (srow & 7)) << 3)] = v;
    }
    // ---- stage B (both gate and up tiles)
    if (is_exp) {
      bf16x8 w[4];
#pragma unroll
      for (int j = 0; j < 8; ++j) {
        const float4 fv = *(const float4*)(Btg + (size_t)(k0 + kch * 8 + j) * (2 * HDIM) + nb4);
        w[0][j]=(bf16)fv.x; w[1][j]=(bf16)fv.y; w[2][j]=(bf16)fv.z; w[3][j]=(bf16)fv.w;
      }
#pragma unroll
      for (int cc = 0; cc < 4; ++cc) {
        const int r = nb4 + cc;
        *(bf16x8*)&sBg[r * 64 + ((kch ^ (r & 7)) << 3)] = w[cc];
      }
#pragma unroll
      for (int j = 0; j < 8; ++j) {
        const float4 fv = *(const float4*)(Btu + (size_t)(k0 + kch * 8 + j) * (2 * HDIM) + nb4);
        w[0][j]=(bf16)fv.x; w[1][j]=(bf16)fv.y; w[2][j]=(bf16)fv.z; w[3][j]=(bf16)fv.w;
      }
#pragma unroll
      for (int cc = 0; cc < 4; ++cc) {
        const int r = nb4 + cc;
        *(bf16x8*)&sBu[r * 64 + ((kch ^ (r & 7)) << 3)] = w[cc];
      }
    } else {
#pragma unroll
      for (int q = 0; q < 4; ++q) {
        const int c = half4 + q;
        const float4 f0 = *(const float4*)(Bdg + k0 + c * 8);
        const float4 f1 = *(const float4*)(Bdg + k0 + c * 8 + 4);
        bf16x8 v;
        v[0]=(bf16)f0.x; v[1]=(bf16)f0.y; v[2]=(bf16)f0.z; v[3]=(bf16)f0.w;
        v[4]=(bf16)f1.x; v[5]=(bf16)f1.y; v[6]=(bf16)f1.z; v[7]=(bf16)f1.w;
        *(bf16x8*)&sBg[srow * 64 + ((c ^ (srow & 7)) << 3)] = v;
        const float4 g0 = *(const float4*)(Bdu + k0 + c * 8);
        const float4 g1 = *(const float4*)(Bdu + k0 + c * 8 + 4);
        v[0]=(bf16)g0.x; v[1]=(bf16)g0.y; v[2]=(bf16)g0.z; v[3]=(bf16)g0.w;
        v[4]=(bf16)g1.x; v[5]=(bf16)g1.y; v[6]=(bf16)g1.z; v[7]=(bf16)g1.w;
        *(bf16x8*)&sBu[srow * 64 + ((c ^ (srow & 7)) << 3)] = v;
      }
    }
    __syncthreads();
    // ---- compute: 32 MFMA per wave per K-step
#pragma unroll
    for (int kk = 0; kk < 2; ++kk) {
      const int ch = kk * 4 + grp;
      bf16x8 av[4], bg[4], bu[4];
#pragma unroll
      for (int m = 0; m < 4; ++m) {
        const int r = wr + m * 16 + lrow;
        av[m] = *(const bf16x8*)&sA[r * 64 + ((ch ^ (r & 7)) << 3)];
      }
#pragma unroll
      for (int n = 0; n < 4; ++n) {
        const int r = wc + n * 16 + lrow;
        bg[n] = *(const bf16x8*)&sBg[r * 64 + ((ch ^ (r & 7)) << 3)];
        bu[n] = *(const bf16x8*)&sBu[r * 64 + ((ch ^ (r & 7)) << 3)];
      }
#pragma unroll
      for (int m = 0; m < 4; ++m)
#pragma unroll
        for (int n = 0; n < 4; ++n) {
          ag[m][n] = __builtin_amdgcn_mfma_f32_16x16x32_bf16(av[m], bg[n], ag[m][n], 0, 0, 0);
          au[m][n] = __builtin_amdgcn_mfma_f32_16x16x32_bf16(av[m], bu[n], au[m][n], 0, 0, 0);
        }
    }
    __syncthreads();
  }
  // ---- SwiGLU epilogue: h = silu(g)*u   (C/D: col=lane&15, row=grp*4+reg)
#pragma unroll
  for (int m = 0; m < 4; ++m) {
#pragma unroll
    for (int i = 0; i < 4; ++i) {
      const int rl = wr + m * 16 + grp * 4 + i;
      if (rl >= mguard) continue;
      bf16* orow = hbase + (size_t)rl * hstride;
#pragma unroll
      for (int n = 0; n < 4; ++n) {
        const float g = ag[m][n][i];
        const float u = au[m][n][i];
        orow[wc + n * 16 + lrow] = (bf16)(g * u * __builtin_amdgcn_rcpf(1.f + __expf(-g)));
      }
    }
  }
}

// ---------------- fused down GEMM, expert+shared in one launch ----------------
// Tile 64 rows x 128 cols, 4 waves (each 32x64). A is bf16 via global_load_lds.
__global__ __launch_bounds__(256)
void down_fused(const bf16* __restrict__ h_exp,
                const bf16* __restrict__ h_sh,
                const float* __restrict__ dw,
                const float* __restrict__ sdw,
                const float* __restrict__ entry_gate,
                bf16* __restrict__ out_e,
                float* __restrict__ out,
                const int* __restrict__ counts,
                const int* __restrict__ offsets,
                const int* __restrict__ tab64,
                const int* __restrict__ ntiles) {
  __shared__ __align__(16) bf16 sA[64 * 64];
  __shared__ __align__(16) bf16 sB[128 * 64];

  const int bid = blockIdx.x;
  const int t = threadIdx.x;
  const bool is_exp = bid < ESLOT64 * 8;
  const int wid = t >> 6, lane = t & 63;

  int n0, mguard, K, rowbase;
  const bf16* Ab;
  const float* Bt = nullptr;   // trans base (expert)
  const float* Bd = nullptr;   // direct per-thread row ptr (shared)

  const int srow  = t >> 1;
  const int half4 = (t & 1) * 4;
  const int kch = t >> 5;
  const int nb4 = (t & 31) * 4;

  if (is_exp) {
    const int slot = bid >> 3;
    if (slot >= ntiles[1]) return;
    const int packed = tab64[slot];
    const int e = packed >> 16;
    const int m0 = packed & 0xffff;
    const int cnt = counts[e];
    const int base = offsets[e];
    n0 = (bid & 7) * 128;
    mguard = cnt - m0;
    K = HDIM;
    rowbase = base + m0;
    Ab = h_exp;
    Bt = dw + (size_t)e * HDIM * CDIM + n0;
  } else {
    const int sid = bid - ESLOT64 * 8;
    const int m0 = (sid >> 3) * 64;
    n0 = (sid & 7) * 128;
    mguard = 64;
    K = SDIM;
    rowbase = m0;
    Ab = h_sh;
    Bd = sdw + (size_t)(n0 + srow) * SDIM;
  }

  // per-lane A sources for global_load_lds (swizzle folded into source addr)
  const bf16* asrc[2];
  int adst[2];
#pragma unroll
  for (int i = 0; i < 2; ++i) {
    const int blkc = wid * 2 + i;               // 0..7 (8 rows each)
    const int row_l = blkc * 8 + (lane >> 3);   // 0..63
    const int c = (lane & 7) ^ (lane >> 3);
    int rg = rowbase + row_l;
    if (is_exp && rg > N_TOK * TOPK - 1) rg = N_TOK * TOPK - 1;
    asrc[i] = Ab + (size_t)rg * K + c * 8;
    adst[i] = blkc * 512;
  }

  const int wr = (wid >> 1) * 32, wc = (wid & 1) * 64;
  const int lrow = lane & 15, grp = lane >> 4;

  f32x4 acc[2][4];
#pragma unroll
  for (int m = 0; m < 2; ++m)
#pragma unroll
    for (int n = 0; n < 4; ++n)
#pragma unroll
      for (int i = 0; i < 4; ++i) acc[m][n][i] = 0.f;

  for (int k0 = 0; k0 < K; k0 += 64) {
#pragma unroll
    for (int i = 0; i < 2; ++i) gload16(asrc[i] + k0, &sA[adst[i]]);
    if (is_exp) {
      bf16x8 w[4];
#pragma unroll
      for (int j = 0; j < 8; ++j) {
        const float4 fv = *(const float4*)(Bt + (size_t)(k0 + kch * 8 + j) * CDIM + nb4);
        w[0][j]=(bf16)fv.x; w[1][j]=(bf16)fv.y; w[2][j]=(bf16)fv.z; w[3][j]=(bf16)fv.w;
      }
#pragma unroll
      for (int cc = 0; cc < 4; ++cc) {
        const int r = nb4 + cc;
        *(bf16x8*)&sB[r * 64 + ((kch ^ (r & 7)) << 3)] = w[cc];
      }
    } else {
#pragma unroll
      for (int q = 0; q < 4; ++q) {
        const int c = half4 + q;
        const float4 f0 = *(const float4*)(Bd + k0 + c * 8);
        const float4 f1 = *(const float4*)(Bd + k0 + c * 8 + 4);
        bf16x8 v;
        v[0]=(bf16)f0.x; v[1]=(bf16)f0.y; v[2]=(bf16)f0.z; v[3]=(bf16)f0.w;
        v[4]=(bf16)f1.x; v[5]=(bf16)f1.y; v[6]=(bf16)f1.z; v[7]=(bf16)f1.w;
        *(bf16x8*)&sB[srow * 64 + ((c ^ (srow & 7)) << 3)] = v;
      }
    }
    __syncthreads();
#pragma unroll
    for (int kk = 0; kk < 2; ++kk) {
      const int ch = kk * 4 + grp;
      bf16x8 av[2], bv[4];
#pragma unroll
      for (int m = 0; m < 2; ++m) {
        const int r = wr + m * 16 + lrow;
        av[m] = *(const bf16x8*)&sA[r * 64 + ((ch ^ (r & 7)) << 3)];
      }
#pragma unroll
      for (int n = 0; n < 4; ++n) {
        const int r = wc + n * 16 + lrow;
        bv[n] = *(const bf16x8*)&sB[r * 64 + ((ch ^ (r & 7)) << 3)];
      }
#pragma unroll
      for (int m = 0; m < 2; ++m)
#pragma unroll
        for (int n = 0; n < 4; ++n)
          acc[m][n] = __builtin_amdgcn_mfma_f32_16x16x32_bf16(av[m], bv[n], acc[m][n], 0, 0, 0);
    }
    __syncthreads();
  }
#pragma unroll
  for (int m = 0; m < 2; ++m) {
#pragma unroll
    for (int i = 0; i < 4; ++i) {
      const int rl = wr + m * 16 + grp * 4 + i;
      if (rl >= mguard) continue;
      if (is_exp) {
        const int row = rowbase + rl;
        const float sc = entry_gate[row];
        bf16* orow = out_e + (size_t)row * CDIM + n0;
#pragma unroll
        for (int n = 0; n < 4; ++n)
          orow[wc + n * 16 + lrow] = (bf16)(acc[m][n][i] * sc);
      } else {
        float* orow = out + (size_t)(rowbase + rl) * CDIM + n0;
#pragma unroll
        for (int n = 0; n < 4; ++n)
          orow[wc + n * 16 + lrow] = acc[m][n][i];
      }
    }
  }
}

// ---------------- combine: out += gated expert outputs (bf16 out_e) ----------------
__global__ void combine_kernel(float* __restrict__ out,
                               const bf16* __restrict__ out_e,
                               const int* __restrict__ entry_pos) {
  int tid = blockIdx.x * blockDim.x + threadIdx.x;  // over N_TOK*CDIM/4
  int n = tid >> 8;
  int c4 = tid & 255;
  int p0 = entry_pos[2 * n];
  int p1 = entry_pos[2 * n + 1];
  float4 v = ((const float4*)out)[tid];
  ushort4 a = *(const ushort4*)((const u16*)out_e + (size_t)p0 * CDIM + c4 * 4);
  ushort4 b = *(const ushort4*)((const u16*)out_e + (size_t)p1 * CDIM + c4 * 4);
  v.x += fromb(a.x) + fromb(b.x);
  v.y += fromb(a.y) + fromb(b.y);
  v.z += fromb(a.z) + fromb(b.z);
  v.w += fromb(a.w) + fromb(b.w);
  ((float4*)out)[tid] = v;
}

extern "C" void kernel_launch(void* const* d_in, const int* in_sizes, int n_in,
                              void* d_out, int out_size, void* d_ws, size_t ws_size,
                              hipStream_t stream) {
  const float* x   = (const float*)d_in[0];
  const float* rw  = (const float*)d_in[1];
  const float* guw = (const float*)d_in[2];
  const float* dw  = (const float*)d_in[3];
  const float* sgw = (const float*)d_in[4];
  const float* suw = (const float*)d_in[5];
  const float* sdw = (const float*)d_in[6];
  float* out = (float*)d_out;
  char* ws = (char*)d_ws;

  int*   sel         = (int*)(ws + 0);
  float* gatew       = (float*)(ws + 16384);
  int*   counts      = (int*)(ws + 32768);
  int*   offsets     = (int*)(ws + 33024);
  int*   cursor      = (int*)(ws + 33280);
  int*   entry_token = (int*)(ws + 33536);
  float* entry_gate  = (float*)(ws + 49920);
  int*   entry_pos   = (int*)(ws + 66304);
  int*   tab128      = (int*)(ws + 82688);
  int*   tab64       = (int*)(ws + 82944);
  int*   ntiles      = (int*)(ws + 83328);
  bf16*  h_exp       = (bf16*)(ws + 83968);                        // 8 MB [4096][1024]
  bf16*  h_sh        = (bf16*)(ws + 83968 + (size_t)8388608);      // 8 MB [2048][2048]
  bf16*  out_e       = (bf16*)(ws + 83968 + (size_t)2 * 8388608);  // 8 MB [4096][1024]

  init_counts_kernel<<<1, 64, 0, stream>>>(counts);
  router_kernel<<<N_TOK, 64, 0, stream>>>(x, rw, sel, gatew, counts);
  scan_kernel<<<1, 64, 0, stream>>>(counts, offsets, cursor, tab128, tab64, ntiles);
  scatter_kernel<<<16, 256, 0, stream>>>(sel, gatew, cursor, entry_token, entry_gate, entry_pos);

  // expert + shared gate_up + SwiGLU (one launch)
  gateup_fused<<<ESLOT128 * 8 + (N_TOK / 128) * (SDIM / 128), 256, 0, stream>>>(
      x, guw, sgw, suw, h_exp, h_sh, counts, offsets, entry_token, tab128, ntiles);

  // expert + shared down (one launch)
  down_fused<<<ESLOT64 * 8 + (N_TOK / 64) * (CDIM / 128), 256, 0, stream>>>(
      h_exp, h_sh, dw, sdw, entry_gate, out_e, out, counts, offsets, tab64, ntiles);

  // add gated expert contributions
  combine_kernel<<<(N_TOK * CDIM / 4) / 256, 256, 0, stream>>>(out, out_e, entry_pos);
}